// Round 3
// baseline (2089.170 us; speedup 1.0000x reference)
//
#include <hip/hip_runtime.h>
#include <stdint.h>

typedef unsigned short u16;
typedef unsigned int u32;
typedef __attribute__((ext_vector_type(4))) float f32x4;
typedef __attribute__((ext_vector_type(8))) short s16x8;

#define T_ 512
#define B_ 256
#define E_ 256
#define H_ 256
#define G3 768

__device__ __forceinline__ u16 f2bf(float f) {
  u32 u = __builtin_bit_cast(u32, f);
  u += 0x7fffu + ((u >> 16) & 1u);
  return (u16)(u >> 16);
}
__device__ __forceinline__ float bf2f(u16 h) {
  u32 u = ((u32)h) << 16;
  return __builtin_bit_cast(float, u);
}

// ---------------- kernel 1: prep (convert weights to bf16, fold biases) ----
__global__ void prep_kernel(const float* __restrict__ Wih, const float* __restrict__ Whh,
                            const float* __restrict__ bih, const float* __restrict__ bhh,
                            u16* __restrict__ Wih_bf, u16* __restrict__ Whh_bf,
                            float* __restrict__ bcomb) {
  int i = blockIdx.x * 256 + threadIdx.x;
  const int n = G3 * E_;  // 196608
  if (i < n) Wih_bf[i] = f2bf(Wih[i]);
  else if (i < 2 * n) Whh_bf[i - n] = f2bf(Whh[i - n]);
  if (i < G3) bcomb[i] = bih[i] + (i < 2 * H_ ? bhh[i] : 0.f);  // n-gate keeps b_hh separate
}

// ---------------- kernel 2: gi = x @ W_ih^T + bcomb  (bf16 MFMA) -----------
__global__ __launch_bounds__(256) void gi_gemm(const float* __restrict__ x,
                                               const u16* __restrict__ Wih_bf,
                                               const float* __restrict__ bcomb,
                                               const int* __restrict__ lengths,
                                               u16* __restrict__ gi) {
  const int m0 = blockIdx.x * 128;          // flat row = t*256 + b
  const int t = m0 >> 8;
  const int bh = (m0 >> 7) & 1;
  if (lengths[bh * 128] <= t) return;       // whole tile inactive (lengths sorted desc)
  const int n0 = blockIdx.y * 128;

  __shared__ u16 As[128 * 256];             // 64 KB, XOR-swizzled
  __shared__ u16 Bs[128 * 256];             // 64 KB

  const int tid = threadIdx.x;
  {
    const float* xt = x + (size_t)m0 * E_;
#pragma unroll
    for (int rep = 0; rep < 32; ++rep) {
      int f = rep * 1024 + tid * 4;
      float4 v = *(const float4*)(xt + f);
      int row = f >> 8, k = f & 255;
      uint2 pv;
      pv.x = ((u32)f2bf(v.y) << 16) | f2bf(v.x);
      pv.y = ((u32)f2bf(v.w) << 16) | f2bf(v.z);
      int byte = (row * 512 + k * 2) ^ ((row & 7) << 4);
      *(uint2*)((char*)As + byte) = pv;
    }
    const u16* wt = Wih_bf + (size_t)n0 * E_;
#pragma unroll
    for (int rep = 0; rep < 32; ++rep) {
      int u = rep * 1024 + tid * 4;
      uint2 v = *(const uint2*)(wt + u);
      int row = u >> 8, k = u & 255;
      int byte = (row * 512 + k * 2) ^ ((row & 7) << 4);
      *(uint2*)((char*)Bs + byte) = v;
    }
  }
  __syncthreads();

  const int lane = tid & 63, wave = tid >> 6;
  const int wm = wave >> 1, wn = wave & 1;
  const int l15 = lane & 15, lhi = lane >> 4;

  f32x4 acc[4][4];
#pragma unroll
  for (int i = 0; i < 4; ++i)
#pragma unroll
    for (int j = 0; j < 4; ++j) acc[i][j] = (f32x4){0.f, 0.f, 0.f, 0.f};

#pragma unroll
  for (int ks = 0; ks < 8; ++ks) {
    s16x8 a[4], b[4];
#pragma unroll
    for (int i = 0; i < 4; ++i) {
      int row = wm * 64 + i * 16 + l15;
      int byte = (row * 512 + (ks * 32 + lhi * 8) * 2) ^ ((row & 7) << 4);
      a[i] = *(const s16x8*)((const char*)As + byte);
    }
#pragma unroll
    for (int j = 0; j < 4; ++j) {
      int row = wn * 64 + j * 16 + l15;
      int byte = (row * 512 + (ks * 32 + lhi * 8) * 2) ^ ((row & 7) << 4);
      b[j] = *(const s16x8*)((const char*)Bs + byte);
    }
#pragma unroll
    for (int i = 0; i < 4; ++i)
#pragma unroll
      for (int j = 0; j < 4; ++j)
        acc[i][j] = __builtin_amdgcn_mfma_f32_16x16x32_bf16(a[i], b[j], acc[i][j], 0, 0, 0);
  }

  // epilogue: +bias, pack adjacent-column bf16 pairs via shfl, dword stores
#pragma unroll
  for (int j = 0; j < 4; ++j) {
    float bc = bcomb[n0 + wn * 64 + j * 16 + l15];
#pragma unroll
    for (int i = 0; i < 4; ++i) {
#pragma unroll
      for (int r = 0; r < 4; ++r) {
        float v = acc[i][j][r] + bc;
        int mybits = (int)f2bf(v);
        int pbits = __shfl_xor(mybits, 1, 64);
        if (!(lane & 1)) {
          int grow = m0 + wm * 64 + i * 16 + 4 * lhi + r;
          int gcol = n0 + wn * 64 + j * 16 + l15;  // even
          *(u32*)((char*)gi + ((size_t)grow * G3 + gcol) * 2) =
              ((u32)pbits << 16) | (u32)mybits;
        }
      }
    }
  }
}

// ---------------- kernel 3: persistent GRU recurrence ----------------------
// 16 wgs x 512 threads (8 waves). wg owns 16 batch rows; wave owns 32 hidden cols.
// ALL 6 W_hh tiles register-resident (192 VGPR). h: fp32 regs (master) + bf16 LDS
// (double-buffered, XOR-swizzled, b32-packed writes via DPP + v_cvt_pk_bf16_f32).
// Per-step sync: lgkmcnt-only drain + raw s_barrier (global loads float across).

__device__ __forceinline__ void gru_step(
    int tt, const u16* __restrict__ gp,
    const s16x8 (&wf)[6][8],
    const u16* __restrict__ hread, u16* __restrict__ hwrite,
    float (&hm)[2][4], const int (&lenr)[4], u32 bhnp,
    int lane, int l15, int lhi, int c0) {

  f32x4 acc[6];
#pragma unroll
  for (int tl = 0; tl < 6; ++tl) acc[tl] = (f32x4){0.f, 0.f, 0.f, 0.f};

  // recurrent GEMM: gh = h @ W_hh^T   (all W resident in VGPRs)
#pragma unroll
  for (int ks = 0; ks < 8; ++ks) {
    int abyte = (l15 * 512 + (ks * 32 + lhi * 8) * 2) ^ ((l15 & 7) << 4);
    s16x8 av = *(const s16x8*)((const char*)hread + abyte);
    acc[0] = __builtin_amdgcn_mfma_f32_16x16x32_bf16(av, wf[0][ks], acc[0], 0, 0, 0);
    acc[1] = __builtin_amdgcn_mfma_f32_16x16x32_bf16(av, wf[1][ks], acc[1], 0, 0, 0);
    acc[2] = __builtin_amdgcn_mfma_f32_16x16x32_bf16(av, wf[2][ks], acc[2], 0, 0, 0);
    acc[3] = __builtin_amdgcn_mfma_f32_16x16x32_bf16(av, wf[3][ks], acc[3], 0, 0, 0);
    acc[4] = __builtin_amdgcn_mfma_f32_16x16x32_bf16(av, wf[4][ks], acc[4], 0, 0, 0);
    acc[5] = __builtin_amdgcn_mfma_f32_16x16x32_bf16(av, wf[5][ks], acc[5], 0, 0, 0);
  }

  // gi loads issued post-MFMA (short live range; ~100cy exposure, dual-wave hides)
  u16 rz[2][2][4];  // [g][hf][r]
#pragma unroll
  for (int g = 0; g < 2; ++g)
#pragma unroll
    for (int hf = 0; hf < 2; ++hf)
#pragma unroll
      for (int r = 0; r < 4; ++r) rz[g][hf][r] = gp[r * G3 + g * 256 + hf * 16];
  u16 nn[2][4];
#pragma unroll
  for (int hf = 0; hf < 2; ++hf)
#pragma unroll
    for (int r = 0; r < 4; ++r) nn[hf][r] = gp[r * G3 + 512 + hf * 16];

  float bhn0 = bf2f((u16)bhnp), bhn1 = bf2f((u16)(bhnp >> 16));

#pragma unroll
  for (int hf = 0; hf < 2; ++hf) {
#pragma unroll
    for (int r = 0; r < 4; ++r) {
      float ir = acc[0 + hf][r] + bf2f(rz[0][hf][r]);
      float iz = acc[2 + hf][r] + bf2f(rz[1][hf][r]);
      float hn = acc[4 + hf][r] + (hf ? bhn1 : bhn0);
      float inn = bf2f(nn[hf][r]);
      float rg = __builtin_amdgcn_rcpf(1.f + __builtin_amdgcn_exp2f(ir * -1.44269504f));
      float zg = __builtin_amdgcn_rcpf(1.f + __builtin_amdgcn_exp2f(iz * -1.44269504f));
      float pre = inn + rg * hn;
      float th = 1.f - 2.f * __builtin_amdgcn_rcpf(1.f + __builtin_amdgcn_exp2f(pre * 2.88539008f));
      float hnew = th + zg * (hm[hf][r] - th);

      // cross-lane pack: adjacent output cols live in adjacent lanes
      int nb = __builtin_bit_cast(int, hnew);
      int ob = __builtin_amdgcn_update_dpp(0, nb, 0xB1, 0xF, 0xF, true);  // quad_perm [1,0,3,2]
      float fo = __builtin_bit_cast(float, ob);
      float lo = (lane & 1) ? fo : hnew;
      float hi = (lane & 1) ? hnew : fo;
      u32 packed;
      asm("v_cvt_pk_bf16_f32 %0, %1, %2" : "=v"(packed) : "v"(lo), "v"(hi));

      if (tt < lenr[r]) {  // packed-seq mask: frozen rows keep state
        hm[hf][r] = hnew;
        if (!(lane & 1)) {
          int m = 4 * lhi + r;
          int colb = (c0 + hf * 16 + (l15 & ~1)) * 2;
          int wbyte = (m * 512 + colb) ^ ((m & 7) << 4);
          *(u32*)((char*)hwrite + wbyte) = packed;
        }
      }
    }
  }

  // raw barrier: drain LDS ops only; global loads stay in flight
  __builtin_amdgcn_sched_barrier(0);
  asm volatile("s_waitcnt lgkmcnt(0)" ::: "memory");
  __builtin_amdgcn_s_barrier();
  __builtin_amdgcn_sched_barrier(0);
}

__global__ __launch_bounds__(512, 2) void gru_rec(const u16* __restrict__ gi,
                                                  const u16* __restrict__ Whh_bf,
                                                  const float* __restrict__ bhh,
                                                  const int* __restrict__ lengths,
                                                  float* __restrict__ hout) {
  const int wg = blockIdx.x;
  const int tid = threadIdx.x;
  const int wave = tid >> 6, lane = tid & 63;
  const int l15 = lane & 15, lhi = lane >> 4;
  const int c0 = wave * 32;

  __shared__ u16 hbf[2][16 * 256];   // 16 KB, XOR-swizzled, double-buffered

  for (int i = tid; i < 16 * 256 / 2; i += 512) ((u32*)hbf[0])[i] = 0;

  // all 6 W_hh tiles resident (B-operand: lane holds W[gate_row=base+l15][k..k+8))
  s16x8 wf[6][8];
#pragma unroll
  for (int tl = 0; tl < 6; ++tl) {
    int g = tl >> 1, hf = tl & 1;
    int row = g * 256 + c0 + hf * 16 + l15;
#pragma unroll
    for (int ks = 0; ks < 8; ++ks)
      wf[tl][ks] = *(const s16x8*)(Whh_bf + (size_t)row * 256 + ks * 32 + lhi * 8);
  }

  u32 bhnp;
  {
    u16 b0 = f2bf(bhh[512 + c0 + l15]);
    u16 b1 = f2bf(bhh[512 + c0 + 16 + l15]);
    bhnp = ((u32)b1 << 16) | b0;
  }
  int lenr[4];
#pragma unroll
  for (int r = 0; r < 4; ++r) lenr[r] = lengths[wg * 16 + 4 * lhi + r];
  const int tmax = lengths[wg * 16];  // max length in this row-group (sorted desc)

  float hm[2][4];
#pragma unroll
  for (int hf = 0; hf < 2; ++hf)
#pragma unroll
    for (int r = 0; r < 4; ++r) hm[hf][r] = 0.f;

  const u16* gp = gi + (size_t)(wg * 16 + 4 * lhi) * G3 + c0 + l15;

  __syncthreads();  // covers hbf zero-init

  for (int t = 0; t < tmax; t += 2) {
    gru_step(t, gp, wf, hbf[0], hbf[1], hm, lenr, bhnp, lane, l15, lhi, c0);
    gp += B_ * G3;
    if (t + 1 < tmax) {
      gru_step(t + 1, gp, wf, hbf[1], hbf[0], hm, lenr, bhnp, lane, l15, lhi, c0);
      gp += B_ * G3;
    }
  }

#pragma unroll
  for (int hf = 0; hf < 2; ++hf)
#pragma unroll
    for (int r = 0; r < 4; ++r)
      hout[(size_t)(wg * 16 + 4 * lhi + r) * 256 + c0 + hf * 16 + l15] = hm[hf][r];
}

// ---------------- kernel 4: gather by unsorted_indices ---------------------
__global__ void gather_kernel(const float* __restrict__ hs, const int* __restrict__ u,
                              float* __restrict__ out) {
  int b = blockIdx.x, c = threadIdx.x;
  out[(size_t)b * 256 + c] = hs[(size_t)u[b] * 256 + c];
}

// ---------------------------------------------------------------------------
extern "C" void kernel_launch(void* const* d_in, const int* in_sizes, int n_in,
                              void* d_out, int out_size, void* d_ws, size_t ws_size,
                              hipStream_t stream) {
  (void)in_sizes; (void)n_in; (void)out_size; (void)ws_size;
  const float* x = (const float*)d_in[0];
  const float* Wih = (const float*)d_in[1];
  const float* Whh = (const float*)d_in[2];
  const float* bih = (const float*)d_in[3];
  const float* bhh = (const float*)d_in[4];
  const int* lengths = (const int*)d_in[5];
  const int* uidx = (const int*)d_in[6];
  float* out = (float*)d_out;

  char* ws = (char*)d_ws;
  u16* gi = (u16*)(ws);                         // 512*256*768*2  = 201326592 B
  u16* Wih_bf = (u16*)(ws + 201326592);         // 393216 B
  u16* Whh_bf = (u16*)(ws + 201719808);         // 393216 B
  float* bcomb = (float*)(ws + 202113024);      // 3072 B
  float* hs = (float*)(ws + 202116096);         // 262144 B

  hipLaunchKernelGGL(prep_kernel, dim3(1536), dim3(256), 0, stream,
                     Wih, Whh, bih, bhh, Wih_bf, Whh_bf, bcomb);
  hipLaunchKernelGGL(gi_gemm, dim3(1024, 6), dim3(256), 0, stream,
                     x, Wih_bf, bcomb, lengths, gi);
  hipLaunchKernelGGL(gru_rec, dim3(16), dim3(512), 0, stream,
                     gi, Whh_bf, bhh, lengths, hs);
  hipLaunchKernelGGL(gather_kernel, dim3(256), dim3(256), 0, stream, hs, uidx, out);
}

// Round 4
// 1331.616 us; speedup vs baseline: 1.5689x; 1.5689x over previous
//
#include <hip/hip_runtime.h>
#include <stdint.h>

typedef unsigned short u16;
typedef unsigned int u32;
typedef __attribute__((ext_vector_type(4))) float f32x4;
typedef __attribute__((ext_vector_type(8))) short s16x8;

#define T_ 512
#define B_ 256
#define E_ 256
#define H_ 256
#define G3 768

__device__ __forceinline__ u16 f2bf(float f) {
  u32 u = __builtin_bit_cast(u32, f);
  u += 0x7fffu + ((u >> 16) & 1u);
  return (u16)(u >> 16);
}
__device__ __forceinline__ float bf2f(u16 h) {
  u32 u = ((u32)h) << 16;
  return __builtin_bit_cast(float, u);
}

// ---------------- kernel 1: prep (convert weights to bf16, fold biases) ----
__global__ void prep_kernel(const float* __restrict__ Wih, const float* __restrict__ Whh,
                            const float* __restrict__ bih, const float* __restrict__ bhh,
                            u16* __restrict__ Wih_bf, u16* __restrict__ Whh_bf,
                            float* __restrict__ bcomb) {
  int i = blockIdx.x * 256 + threadIdx.x;
  const int n = G3 * E_;  // 196608
  if (i < n) Wih_bf[i] = f2bf(Wih[i]);
  else if (i < 2 * n) Whh_bf[i - n] = f2bf(Whh[i - n]);
  if (i < G3) bcomb[i] = bih[i] + (i < 2 * H_ ? bhh[i] : 0.f);  // n-gate keeps b_hh separate
}

// ---------------- kernel 2: gi = x @ W_ih^T + bcomb  (bf16 MFMA) -----------
__global__ __launch_bounds__(256) void gi_gemm(const float* __restrict__ x,
                                               const u16* __restrict__ Wih_bf,
                                               const float* __restrict__ bcomb,
                                               const int* __restrict__ lengths,
                                               u16* __restrict__ gi) {
  const int m0 = blockIdx.x * 128;          // flat row = t*256 + b
  const int t = m0 >> 8;
  const int bh = (m0 >> 7) & 1;
  if (lengths[bh * 128] <= t) return;       // whole tile inactive (lengths sorted desc)
  const int n0 = blockIdx.y * 128;

  __shared__ u16 As[128 * 256];             // 64 KB, XOR-swizzled
  __shared__ u16 Bs[128 * 256];             // 64 KB

  const int tid = threadIdx.x;
  {
    const float* xt = x + (size_t)m0 * E_;
#pragma unroll
    for (int rep = 0; rep < 32; ++rep) {
      int f = rep * 1024 + tid * 4;
      float4 v = *(const float4*)(xt + f);
      int row = f >> 8, k = f & 255;
      uint2 pv;
      pv.x = ((u32)f2bf(v.y) << 16) | f2bf(v.x);
      pv.y = ((u32)f2bf(v.w) << 16) | f2bf(v.z);
      int byte = (row * 512 + k * 2) ^ ((row & 7) << 4);
      *(uint2*)((char*)As + byte) = pv;
    }
    const u16* wt = Wih_bf + (size_t)n0 * E_;
#pragma unroll
    for (int rep = 0; rep < 32; ++rep) {
      int u = rep * 1024 + tid * 4;
      uint2 v = *(const uint2*)(wt + u);
      int row = u >> 8, k = u & 255;
      int byte = (row * 512 + k * 2) ^ ((row & 7) << 4);
      *(uint2*)((char*)Bs + byte) = v;
    }
  }
  __syncthreads();

  const int lane = tid & 63, wave = tid >> 6;
  const int wm = wave >> 1, wn = wave & 1;
  const int l15 = lane & 15, lhi = lane >> 4;

  f32x4 acc[4][4];
#pragma unroll
  for (int i = 0; i < 4; ++i)
#pragma unroll
    for (int j = 0; j < 4; ++j) acc[i][j] = (f32x4){0.f, 0.f, 0.f, 0.f};

#pragma unroll
  for (int ks = 0; ks < 8; ++ks) {
    s16x8 a[4], b[4];
#pragma unroll
    for (int i = 0; i < 4; ++i) {
      int row = wm * 64 + i * 16 + l15;
      int byte = (row * 512 + (ks * 32 + lhi * 8) * 2) ^ ((row & 7) << 4);
      a[i] = *(const s16x8*)((const char*)As + byte);
    }
#pragma unroll
    for (int j = 0; j < 4; ++j) {
      int row = wn * 64 + j * 16 + l15;
      int byte = (row * 512 + (ks * 32 + lhi * 8) * 2) ^ ((row & 7) << 4);
      b[j] = *(const s16x8*)((const char*)Bs + byte);
    }
#pragma unroll
    for (int i = 0; i < 4; ++i)
#pragma unroll
      for (int j = 0; j < 4; ++j)
        acc[i][j] = __builtin_amdgcn_mfma_f32_16x16x32_bf16(a[i], b[j], acc[i][j], 0, 0, 0);
  }

  // epilogue: +bias, pack adjacent-column bf16 pairs via shfl, dword stores
#pragma unroll
  for (int j = 0; j < 4; ++j) {
    float bc = bcomb[n0 + wn * 64 + j * 16 + l15];
#pragma unroll
    for (int i = 0; i < 4; ++i) {
#pragma unroll
      for (int r = 0; r < 4; ++r) {
        float v = acc[i][j][r] + bc;
        int mybits = (int)f2bf(v);
        int pbits = __shfl_xor(mybits, 1, 64);
        if (!(lane & 1)) {
          int grow = m0 + wm * 64 + i * 16 + 4 * lhi + r;
          int gcol = n0 + wn * 64 + j * 16 + l15;  // even
          *(u32*)((char*)gi + ((size_t)grow * G3 + gcol) * 2) =
              ((u32)pbits << 16) | (u32)mybits;
        }
      }
    }
  }
}

// ---------------- kernel 3: persistent GRU recurrence ----------------------
// 16 wgs x 512 threads (8 waves). wg owns 16 batch rows; wave owns 32 hidden cols.
// W_hh: 5 tiles register-resident (160 VGPR), 1 tile (n,hf1) in LDS.
// gi: ALL 24 u16 values prefetched one step ahead into regs (single buffer).
// h: fp32 regs (master) + bf16 LDS (dbuf, XOR-swizzled, b32-packed DPP writes).
// Per-step sync: lgkmcnt-only drain + raw s_barrier (global loads float across).

__device__ __forceinline__ void gru_step(
    int tt, const u16* __restrict__ gpn,   // next step's gi base (clamped)
    const s16x8 (&wf)[5][8], const u16* __restrict__ wl5,  // per-wave LDS region
    const u16* __restrict__ hread, u16* __restrict__ hwrite,
    u16 (&pc)[24],                          // [r*6 + g*2 + hf]
    float (&hm)[2][4], const int (&lenr)[4], float bhn0, float bhn1,
    int lane, int l15, int lhi, int c0) {

  // init accumulators from prefetched r,z gi (biases folded) + n bias
  f32x4 acc[6];
#pragma unroll
  for (int tl = 0; tl < 4; ++tl)
#pragma unroll
    for (int r = 0; r < 4; ++r) acc[tl][r] = bf2f(pc[r * 6 + tl]);
  acc[4] = (f32x4){bhn0, bhn0, bhn0, bhn0};
  acc[5] = (f32x4){bhn1, bhn1, bhn1, bhn1};
  float inn[2][4];
#pragma unroll
  for (int hf = 0; hf < 2; ++hf)
#pragma unroll
    for (int r = 0; r < 4; ++r) inn[hf][r] = bf2f(pc[r * 6 + 4 + hf]);

  // recurrent GEMM: gh += h @ W_hh^T  (5 tiles from VGPR, 1 from LDS)
#pragma unroll
  for (int ks = 0; ks < 8; ++ks) {
    int abyte = (l15 * 512 + (ks * 32 + lhi * 8) * 2) ^ ((l15 & 7) << 4);
    s16x8 av = *(const s16x8*)((const char*)hread + abyte);
    acc[0] = __builtin_amdgcn_mfma_f32_16x16x32_bf16(av, wf[0][ks], acc[0], 0, 0, 0);
    acc[1] = __builtin_amdgcn_mfma_f32_16x16x32_bf16(av, wf[1][ks], acc[1], 0, 0, 0);
    acc[2] = __builtin_amdgcn_mfma_f32_16x16x32_bf16(av, wf[2][ks], acc[2], 0, 0, 0);
    acc[3] = __builtin_amdgcn_mfma_f32_16x16x32_bf16(av, wf[3][ks], acc[3], 0, 0, 0);
    acc[4] = __builtin_amdgcn_mfma_f32_16x16x32_bf16(av, wf[4][ks], acc[4], 0, 0, 0);
    s16x8 b5 = *(const s16x8*)(wl5 + ks * 512 + lane * 8);
    acc[5] = __builtin_amdgcn_mfma_f32_16x16x32_bf16(av, b5, acc[5], 0, 0, 0);
  }

  // gates + h update
#pragma unroll
  for (int hf = 0; hf < 2; ++hf) {
#pragma unroll
    for (int r = 0; r < 4; ++r) {
      float ir = acc[0 + hf][r];
      float iz = acc[2 + hf][r];
      float hn = acc[4 + hf][r];
      float rg = __builtin_amdgcn_rcpf(1.f + __builtin_amdgcn_exp2f(ir * -1.44269504f));
      float zg = __builtin_amdgcn_rcpf(1.f + __builtin_amdgcn_exp2f(iz * -1.44269504f));
      float pre = inn[hf][r] + rg * hn;
      float th = 1.f - 2.f * __builtin_amdgcn_rcpf(1.f + __builtin_amdgcn_exp2f(pre * 2.88539008f));
      float hnew = th + zg * (hm[hf][r] - th);
      // unconditional select: frozen rows keep (and rewrite) their old state
      float hsel = (tt < lenr[r]) ? hnew : hm[hf][r];
      hm[hf][r] = hsel;

      // cross-lane pack: adjacent output cols live in adjacent lanes
      int nb = __builtin_bit_cast(int, hsel);
      int ob = __builtin_amdgcn_update_dpp(0, nb, 0xB1, 0xF, 0xF, true);  // quad_perm [1,0,3,2]
      float fo = __builtin_bit_cast(float, ob);
      float lo = (lane & 1) ? fo : hsel;
      float hi = (lane & 1) ? hsel : fo;
      u32 packed;
      asm("v_cvt_pk_bf16_f32 %0, %1, %2" : "=v"(packed) : "v"(lo), "v"(hi));
      if (!(lane & 1)) {
        int m = 4 * lhi + r;
        int colb = (c0 + hf * 16 + (l15 & ~1)) * 2;
        int wbyte = (m * 512 + colb) ^ ((m & 7) << 4);
        *(u32*)((char*)hwrite + wbyte) = packed;
      }
    }
  }

  // prefetch next step's full gi slice (r,z,n) -- consumed next step
#pragma unroll
  for (int r = 0; r < 4; ++r)
#pragma unroll
    for (int g = 0; g < 3; ++g)
#pragma unroll
      for (int hf = 0; hf < 2; ++hf)
        pc[r * 6 + g * 2 + hf] = gpn[r * G3 + g * 256 + hf * 16];

  // raw barrier: drain LDS ops only; global loads stay in flight
  __builtin_amdgcn_sched_barrier(0);
  asm volatile("s_waitcnt lgkmcnt(0)" ::: "memory");
  __builtin_amdgcn_s_barrier();
  __builtin_amdgcn_sched_barrier(0);
}

__global__ __launch_bounds__(512, 2) void gru_rec(const u16* __restrict__ gi,
                                                  const u16* __restrict__ Whh_bf,
                                                  const float* __restrict__ bhh,
                                                  const int* __restrict__ lengths,
                                                  float* __restrict__ hout) {
  const int wg = blockIdx.x;
  const int tid = threadIdx.x;
  const int wave = tid >> 6, lane = tid & 63;
  const int l15 = lane & 15, lhi = lane >> 4;
  const int c0 = wave * 32;

  __shared__ u16 hbf[2][16 * 256];   // 16 KB, XOR-swizzled, double-buffered
  __shared__ u16 wl[8 * 8 * 512];    // 64 KB: (n,hf1) tile B-fragments, lane-linear

  for (int i = tid; i < 16 * 256 / 2; i += 512) ((u32*)hbf[0])[i] = 0;

  // 5 W_hh tiles resident (B-operand: lane holds W[gate_row=base+l15][k..k+8))
  s16x8 wf[5][8];
#pragma unroll
  for (int tl = 0; tl < 5; ++tl) {
    int g = tl >> 1, hf = tl & 1;
    int row = g * 256 + c0 + hf * 16 + l15;
#pragma unroll
    for (int ks = 0; ks < 8; ++ks)
      wf[tl][ks] = *(const s16x8*)(Whh_bf + (size_t)row * 256 + ks * 32 + lhi * 8);
  }
  // 6th tile (n, hf=1) -> LDS
  {
    int row = 512 + c0 + 16 + l15;
#pragma unroll
    for (int ks = 0; ks < 8; ++ks) {
      s16x8 v = *(const s16x8*)(Whh_bf + (size_t)row * 256 + ks * 32 + lhi * 8);
      *(s16x8*)(&wl[(wave * 8 + ks) * 512 + lane * 8]) = v;
    }
  }
  const u16* wl5 = &wl[wave * 8 * 512];

  float bhn0 = bhh[512 + c0 + l15];
  float bhn1 = bhh[512 + c0 + 16 + l15];
  int lenr[4];
#pragma unroll
  for (int r = 0; r < 4; ++r) lenr[r] = lengths[wg * 16 + 4 * lhi + r];
  const int tmax = lengths[wg * 16];  // max length in this row-group (sorted desc)

  float hm[2][4];
#pragma unroll
  for (int hf = 0; hf < 2; ++hf)
#pragma unroll
    for (int r = 0; r < 4; ++r) hm[hf][r] = 0.f;

  const u16* gp0 = gi + (size_t)(wg * 16 + 4 * lhi) * G3 + c0 + l15;

  // preload t=0 gi (all gates)
  u16 pc[24];
#pragma unroll
  for (int r = 0; r < 4; ++r)
#pragma unroll
    for (int g = 0; g < 3; ++g)
#pragma unroll
      for (int hf = 0; hf < 2; ++hf)
        pc[r * 6 + g * 2 + hf] = gp0[r * G3 + g * 256 + hf * 16];

  __syncthreads();  // covers hbf zero-init + wl staging

  for (int t = 0; t < tmax; t += 2) {
    const u16* gp1 = gp0 + (t + 1 < tmax ? (size_t)(t + 1) * (B_ * G3) : (size_t)t * (B_ * G3));
    gru_step(t, gp1, wf, wl5, hbf[0], hbf[1], pc, hm, lenr, bhn0, bhn1,
             lane, l15, lhi, c0);
    if (t + 1 < tmax) {
      const u16* gp2 = gp0 + (t + 2 < tmax ? (size_t)(t + 2) * (B_ * G3) : (size_t)(t + 1) * (B_ * G3));
      gru_step(t + 1, gp2, wf, wl5, hbf[1], hbf[0], pc, hm, lenr, bhn0, bhn1,
               lane, l15, lhi, c0);
    }
  }

#pragma unroll
  for (int hf = 0; hf < 2; ++hf)
#pragma unroll
    for (int r = 0; r < 4; ++r)
      hout[(size_t)(wg * 16 + 4 * lhi + r) * 256 + c0 + hf * 16 + l15] = hm[hf][r];
}

// ---------------- kernel 4: gather by unsorted_indices ---------------------
__global__ void gather_kernel(const float* __restrict__ hs, const int* __restrict__ u,
                              float* __restrict__ out) {
  int b = blockIdx.x, c = threadIdx.x;
  out[(size_t)b * 256 + c] = hs[(size_t)u[b] * 256 + c];
}

// ---------------------------------------------------------------------------
extern "C" void kernel_launch(void* const* d_in, const int* in_sizes, int n_in,
                              void* d_out, int out_size, void* d_ws, size_t ws_size,
                              hipStream_t stream) {
  (void)in_sizes; (void)n_in; (void)out_size; (void)ws_size;
  const float* x = (const float*)d_in[0];
  const float* Wih = (const float*)d_in[1];
  const float* Whh = (const float*)d_in[2];
  const float* bih = (const float*)d_in[3];
  const float* bhh = (const float*)d_in[4];
  const int* lengths = (const int*)d_in[5];
  const int* uidx = (const int*)d_in[6];
  float* out = (float*)d_out;

  char* ws = (char*)d_ws;
  u16* gi = (u16*)(ws);                         // 512*256*768*2  = 201326592 B
  u16* Wih_bf = (u16*)(ws + 201326592);         // 393216 B
  u16* Whh_bf = (u16*)(ws + 201719808);         // 393216 B
  float* bcomb = (float*)(ws + 202113024);      // 3072 B
  float* hs = (float*)(ws + 202116096);         // 262144 B

  hipLaunchKernelGGL(prep_kernel, dim3(1536), dim3(256), 0, stream,
                     Wih, Whh, bih, bhh, Wih_bf, Whh_bf, bcomb);
  hipLaunchKernelGGL(gi_gemm, dim3(1024, 6), dim3(256), 0, stream,
                     x, Wih_bf, bcomb, lengths, gi);
  hipLaunchKernelGGL(gru_rec, dim3(16), dim3(512), 0, stream,
                     gi, Whh_bf, bhh, lengths, hs);
  hipLaunchKernelGGL(gather_kernel, dim3(256), dim3(256), 0, stream, hs, uidx, out);
}